// Round 3
// baseline (274.970 us; speedup 1.0000x reference)
//
#include <hip/hip_runtime.h>

// Reference numpy/jnp math is UNFUSED IEEE f32 — disable FMA contraction so
// the catastrophically-cancelled det (compared against EPS=1e-7) and the
// 1/det-scaled shifts are bit-identical to the reference.
#pragma clang fp contract(off)

// Problem constants (from setup_inputs): B=2, C=4, D=6, H=512, W=512, f32.
constexpr int B_ = 2, C_ = 4, D_ = 6, H_ = 512, W_ = 512;
constexpr int HW_  = H_ * W_;        // 262144
constexpr int DHW_ = D_ * HW_;       // 1572864
constexpr int BC_  = B_ * C_;        // 8
constexpr int TOT_ = BC_ * DHW_;     // 12582912

#define EPS_ 1e-7f
#define MAX_SHIFT_ 0.6f
#define BONUS_ 10.0f
#define N_ITERS_ 5

// Clang native vectors — accepted by __builtin_nontemporal_store (HIP's
// float4 is a struct and is rejected).
typedef float f32x4 __attribute__((ext_vector_type(4)));
typedef int   i32x4 __attribute__((ext_vector_type(4)));

// ---------------------------------------------------------------------------
// 3x3x3 quadratic-fit Cramer solve; p points at the (interior) center voxel.
// Op ordering mirrors the reference exactly (f32, no contraction).
__device__ __forceinline__ void solve3(const float* __restrict__ p,
                                       float& sx, float& sy, float& ss,
                                       float& gds, bool& sol)
{
    #pragma clang fp contract(off)
    float c    = p[0];
    float xp   = p[1],          xm   = p[-1];
    float yp   = p[W_],         ym   = p[-W_];
    float spv  = p[HW_],        smv  = p[-HW_];
    float xpyp = p[W_ + 1],     xmyp = p[W_ - 1];
    float xpym = p[-W_ + 1],    xmym = p[-W_ - 1];
    float xpsp = p[HW_ + 1],    xmsp = p[HW_ - 1];
    float xpsm = p[-HW_ + 1],   xmsm = p[-HW_ - 1];
    float ypsp = p[HW_ + W_],   ymsp = p[HW_ - W_];
    float ypsm = p[-HW_ + W_],  ymsm = p[-HW_ - W_];

    float gx = 0.5f * (xp - xm);
    float gy = 0.5f * (yp - ym);
    float gs = 0.5f * (spv - smv);
    float dxx = xp - 2.0f * c + xm;
    float dyy = yp - 2.0f * c + ym;
    float dss = spv - 2.0f * c + smv;
    float dxy = 0.25f * (xpyp - xmyp - xpym + xmym);
    float dxs = 0.25f * (xpsp - xmsp - xpsm + xmsm);
    float dys = 0.25f * (ypsp - ymsp - ypsm + ymsm);

    float cf00 = dyy * dss - dys * dys;
    float cf01 = dxy * dss - dys * dxs;
    float cf02 = dxy * dys - dyy * dxs;
    float det  = dxx * cf00 - dxy * cf01 + dxs * cf02;
    sol = fabsf(det) > EPS_;
    float sd = sol ? det : 1.0f;
    float r0 = -gx, r1 = -gy, r2 = -gs;
    sx = (r0 * cf00 - dxy * (r1 * dss - dys * r2) + dxs * (r1 * dys - dyy * r2)) / sd;
    sy = (dxx * (r1 * dss - dys * r2) - r0 * cf01 + dxs * (dxy * r2 - r1 * dxs)) / sd;
    ss = (dxx * (dyy * r2 - r1 * dys) - dxy * (dxy * r2 - r1 * dxs) + r0 * cf02) / sd;
    gds = gx * sx + gy * sy + gs * ss;
}

// ---------------------------------------------------------------------------
// One fused pass, one thread per FOUR consecutive-w voxels (W=512 % 4 == 0,
// so all 4 share bc,d,h). All memory traffic is dwordx4 (16 B/lane):
//   load f32x4 x, i32x4 mask; compute 4 default outputs in scalar registers;
//   patch the rare (0.1%) seed elements in-register via the exact walk;
//   one nontemporal dwordx4 store per output stream.
__global__ __launch_bounds__(256)
void AdaptiveQuadInterp3d_kernel(const float* __restrict__ x,
                                 const int* __restrict__ mask,
                                 float* __restrict__ out)
{
    int tid = blockIdx.x * 256 + threadIdx.x;
    int e   = tid * 4;                 // first voxel of this thread's group

    int w0 = e & (W_ - 1);             // multiple of 4
    int h  = (e >> 9) & (H_ - 1);
    int t  = e >> 18;                  // bc*D + d   (HW = 2^18)
    int d  = t % D_;
    int bc = t / D_;
    int sp = e - bc * DHW_;

    const f32x4 xv = *reinterpret_cast<const f32x4*>(x + e);
    const i32x4 mv = *reinterpret_cast<const i32x4*>(mask + e);

    // Default outputs in scalar registers (vector elements can't bind to
    // non-const refs; scalars regalloc identically).
    float fd = (float)d, fh = (float)h;
    float cs0 = fd, cs1 = fd, cs2 = fd, cs3 = fd;
    float cx0 = (float)w0,       cx1 = (float)(w0 + 1);
    float cx2 = (float)(w0 + 2), cx3 = (float)(w0 + 3);
    float cy0 = fh, cy1 = fh, cy2 = fh, cy3 = fh;
    float y0 = xv.x, y1 = xv.y, y2 = xv.z, y3 = xv.w;

    int anym = mv.x | mv.y | mv.z | mv.w;

    // Wave-uniform skip: 0.999^256 ≈ 77% of waves have no seeds at all.
    if (__ballot(anym != 0) != 0ULL) {
        if (anym != 0) {
            const float* xb = x + bc * DHW_;

            // Exact walk for one seed element; patches the register outputs.
            auto walk = [&](int mj, int w, float xc,
                            float& cs, float& cx, float& cy, float& yy) {
                #pragma clang fp contract(off)
                if (mj == 0) return;
                int dsd = 0, dsh = 0, dsw = 0;
                bool valid = true;
                float shx = 0.0f, shy = 0.0f, shs = 0.0f, gk = 0.0f;

                // Exact early termination:
                //  - !sol → valid false forever, outputs are defaults (+BONUS on y).
                //  - valid with all-zero steps = fixed point: later iterations
                //    recompute identical values. Bit-exact vs reference.
                #pragma unroll 1
                for (int it = 0; it < N_ITERS_; ++it) {
                    int di = min(max(d + dsd, 1), D_ - 2);
                    int hi = min(max(h + dsh, 1), H_ - 2);
                    int wi = min(max(w + dsw, 1), W_ - 2);
                    const float* p = xb + di * HW_ + hi * W_ + wi;

                    float sx, sy, ssv, gds; bool sol;
                    solve3(p, sx, sy, ssv, gds, sol);

                    if (!sol) { valid = false; break; }

                    shx = sx; shy = sy; shs = ssv; gk = gds;

                    int stx = (shx > MAX_SHIFT_) ? 1 : ((shx < -MAX_SHIFT_) ? -1 : 0);
                    int sty = (shy > MAX_SHIFT_) ? 1 : ((shy < -MAX_SHIFT_) ? -1 : 0);
                    int sts = (shs > MAX_SHIFT_) ? 1 : ((shs < -MAX_SHIFT_) ? -1 : 0);
                    dsw += stx;
                    dsh += sty;
                    dsd += sts;
                    valid = (abs(dsd) <= 1) && (abs(dsh) <= 1) && (abs(dsw) <= 1);
                    if (!valid) break;                  // radius breach — exact
                    if ((stx | sty | sts) == 0) break;  // fixed point — exact
                }

                if (valid) {
                    int di = min(max(d + dsd, 1), D_ - 2);
                    int hi = min(max(h + dsh, 1), H_ - 2);
                    int wi = min(max(w + dsw, 1), W_ - 2);
                    float cur = xb[di * HW_ + hi * W_ + wi];
                    cs = (float)(d + dsd) + shs;
                    cx = (float)(w + dsw) + shx;
                    cy = (float)(h + dsh) + shy;
                    yy = (cur + 0.5f * gk) + BONUS_;
                } else {
                    yy = xc + BONUS_;   // coord registers keep their defaults
                }
            };

            walk(mv.x, w0 + 0, xv.x, cs0, cx0, cy0, y0);
            walk(mv.y, w0 + 1, xv.y, cs1, cx1, cy1, y1);
            walk(mv.z, w0 + 2, xv.z, cs2, cx2, cy2, y2);
            walk(mv.w, w0 + 3, xv.w, cs3, cx3, cy3, y3);
        }
    }

    f32x4 csv = { cs0, cs1, cs2, cs3 };
    f32x4 cxv = { cx0, cx1, cx2, cx3 };
    f32x4 cyv = { cy0, cy1, cy2, cy3 };
    f32x4 yv  = { y0,  y1,  y2,  y3  };

    // Coords layout: (B,C,3,D,H,W) → stream k at out + (bc*3 + k)*DHW + sp.
    float* cb = out + (bc * 3) * DHW_ + sp;
    __builtin_nontemporal_store(csv, reinterpret_cast<f32x4*>(cb));
    __builtin_nontemporal_store(cxv, reinterpret_cast<f32x4*>(cb + DHW_));
    __builtin_nontemporal_store(cyv, reinterpret_cast<f32x4*>(cb + 2 * DHW_));
    // y_max at out + BC*3*DHW + e.
    __builtin_nontemporal_store(yv,
        reinterpret_cast<f32x4*>(out + BC_ * 3 * DHW_ + e));
}

extern "C" void kernel_launch(void* const* d_in, const int* in_sizes, int n_in,
                              void* d_out, int out_size, void* d_ws, size_t ws_size,
                              hipStream_t stream) {
    const float* x    = (const float*)d_in[0];
    const int*   mask = (const int*)d_in[1];
    float*       out  = (float*)d_out;

    int blocks = TOT_ / (256 * 4);   // 12288
    AdaptiveQuadInterp3d_kernel<<<blocks, 256, 0, stream>>>(x, mask, out);
}